// Round 1
// 289.858 us; speedup vs baseline: 1.0283x; 1.0283x over previous
//
#include <hip/hip_runtime.h>
#include <stdint.h>

#define HDIM  768
#define VOCAB 30522
#define NNODE 10002      // NEW_ROWS - 2
#define NEDGE 50000
#define NROWS 10004
#define SLOPE 0.2f

// ---------- ws layout (bytes) ----------
constexpr size_t SZ_HB     = (size_t)NNODE * HDIM * 2;        // 15,363,072
constexpr size_t SZ_F32    = (size_t)NNODE * HDIM * 4;        // 30,726,144
constexpr size_t OFF_H     = 0;                               // h (bf16)
constexpr size_t OFF_FB    = OFF_H  + SZ_HB;                  // featbf (bf16)
constexpr size_t OFF_FO    = OFF_FB + SZ_HB;                  // feat_out (f32)
constexpr size_t OFF_WT    = OFF_FO + SZ_F32;                 // W^T bf16
constexpr size_t SZ_WT     = (size_t)HDIM * HDIM * 2;
constexpr size_t OFF_WAS   = OFF_WT + SZ_WT;
constexpr size_t OFF_WAD   = OFF_WAS + HDIM * 4;
constexpr size_t OFF_SS    = OFF_WAD + HDIM * 4;              // s_src f32[NNODE]
constexpr size_t SZ_N4     = 40032;                           // (NNODE+1)*4 padded
constexpr size_t OFF_SD    = OFF_SS  + SZ_N4;
constexpr size_t OFF_CNT   = OFF_SD  + SZ_N4;                 // histogram (zeroed)
constexpr size_t OFF_START = OFF_CNT + SZ_N4;                 // CSR offsets [NNODE+1]
constexpr size_t OFF_CUR   = OFF_START + SZ_N4;               // scatter cursors
constexpr size_t OFF_ESRC  = OFF_CUR + SZ_N4;                 // sorted src  [NEDGE]
constexpr size_t OFF_ESC   = OFF_ESRC + NEDGE * 4;            // sorted score[NEDGE]

// ---------- helpers ----------
__device__ __forceinline__ unsigned short f2bf(float f) {
  unsigned int u = __float_as_uint(f);
  u += 0x7FFFu + ((u >> 16) & 1u);
  return (unsigned short)(u >> 16);
}
__device__ __forceinline__ float bf2f(unsigned short b) {
  return __uint_as_float(((unsigned int)b) << 16);
}

typedef __attribute__((ext_vector_type(8))) short bf16x8;
typedef __attribute__((ext_vector_type(4))) float f32x4;

__device__ __forceinline__ void gl2lds16(const unsigned short* g, unsigned short* l) {
  __builtin_amdgcn_global_load_lds(
      (const __attribute__((address_space(1))) unsigned int*)g,
      (__attribute__((address_space(3))) unsigned int*)l, 16, 0, 0);
}

// ---------- L1: prep (W^T + wa vectors) + hist, fused ----------
// blocks 0..575: transpose tiles; 576..767: wa rows; 768..963: dst histogram
__global__ __launch_bounds__(256) void k_front(const float* __restrict__ W,
                                               const float* __restrict__ a_s,
                                               const float* __restrict__ a_d,
                                               const int* __restrict__ ei,
                                               unsigned short* __restrict__ wT,
                                               float* __restrict__ wa_s,
                                               float* __restrict__ wa_d,
                                               int* __restrict__ count) {
  int bid = blockIdx.x, tid = threadIdx.x;
  if (bid >= 768) {                      // histogram over dst
    int e = (bid - 768) * 256 + tid;
    if (e < NEDGE) atomicAdd(count + ei[NEDGE + e], 1);
    return;
  }
  if (bid < 576) {                       // 24x24 tiles of 32x32 transpose
    __shared__ float tile[32][33];
    int tx0 = (bid % 24) * 32, ty0 = (bid / 24) * 32;
    int cx = tid & 31, cy = tid >> 5;    // cy 0..7
#pragma unroll
    for (int r = 0; r < 4; ++r)
      tile[cy + r * 8][cx] = W[(size_t)(ty0 + cy + r * 8) * HDIM + tx0 + cx];
    __syncthreads();
#pragma unroll
    for (int r = 0; r < 4; ++r)
      wT[(size_t)(tx0 + cy + r * 8) * HDIM + ty0 + cx] = f2bf(tile[cx][cy + r * 8]);
  } else {                               // wa rows: 192 blocks * 4 waves = 768 rows
    int lane = tid & 63, wid = tid >> 6;
    int row = (bid - 576) * 4 + wid;
    float ss = 0.f, sd = 0.f;
    for (int n = lane; n < HDIM; n += 64) {
      float w = W[(size_t)row * HDIM + n];
      ss += w * a_s[n];
      sd += w * a_d[n];
    }
#pragma unroll
    for (int off = 32; off; off >>= 1) {
      ss += __shfl_down(ss, off, 64);
      sd += __shfl_down(sd, off, 64);
    }
    if (lane == 0) { wa_s[row] = ss; wa_d[row] = sd; }
  }
}

// ---------- L2: convert+scores (blocks 0..2500) + exclusive scan (block 2501) ----------
__global__ __launch_bounds__(256) void k_mid(const float* __restrict__ feat,
                                             const float* __restrict__ wa_s,
                                             const float* __restrict__ wa_d,
                                             unsigned short* __restrict__ featbf,
                                             float* __restrict__ s_s,
                                             float* __restrict__ s_d,
                                             const int* __restrict__ count,
                                             int* __restrict__ startArr,
                                             int* __restrict__ cursor) {
  if (blockIdx.x == 2501) {              // single-block exclusive scan
    __shared__ int part[256];
    int tid = threadIdx.x;
    int base = tid * 40;                 // 40*256 = 10240 >= NNODE
    int loc[40];
    int s = 0;
#pragma unroll
    for (int i = 0; i < 40; ++i) {
      int idx = base + i;
      int c = (idx < NNODE) ? count[idx] : 0;
      loc[i] = s; s += c;
    }
    part[tid] = s;
    __syncthreads();
    for (int d = 1; d < 256; d <<= 1) {
      int t = (tid >= d) ? part[tid - d] : 0;
      __syncthreads();
      part[tid] += t;
      __syncthreads();
    }
    int excl = part[tid] - s;
#pragma unroll
    for (int i = 0; i < 40; ++i) {
      int idx = base + i;
      if (idx < NNODE) {
        int v = excl + loc[i];
        startArr[idx] = v;
        cursor[idx] = v;
      }
    }
    if (tid == 255) startArr[NNODE] = part[255];
    return;
  }
  // convert + fused score dot-products
  int lane = threadIdx.x & 63, wid = threadIdx.x >> 6;
  int r = blockIdx.x * 4 + wid;
  if (r >= NNODE) return;
  const float4* fr = (const float4*)(feat + (size_t)r * HDIM);
  ushort4* ob = (ushort4*)(featbf + (size_t)r * HDIM);
  float ss = 0.f, sd = 0.f;
#pragma unroll
  for (int i = 0; i < 3; ++i) {
    int c = lane + i * 64;               // float4 chunk 0..191
    float4 v = fr[c];
    float4 vs = ((const float4*)wa_s)[c];
    float4 vd = ((const float4*)wa_d)[c];
    ss += v.x * vs.x + v.y * vs.y + v.z * vs.z + v.w * vs.w;
    sd += v.x * vd.x + v.y * vd.y + v.z * vd.z + v.w * vd.w;
    ushort4 o;
    o.x = f2bf(v.x); o.y = f2bf(v.y); o.z = f2bf(v.z); o.w = f2bf(v.w);
    ob[c] = o;
  }
#pragma unroll
  for (int off = 32; off; off >>= 1) {
    ss += __shfl_down(ss, off, 64);
    sd += __shfl_down(sd, off, 64);
  }
  if (lane == 0) { s_s[r] = ss; s_d[r] = sd; }
}

// ---------- L3: GEMM h = feat @ W (128x64 tiles, blocks 0..947) + scatter (948..1143) ----------
__global__ __launch_bounds__(256) void k_main(const unsigned short* __restrict__ A,
                                              const unsigned short* __restrict__ BT,
                                              unsigned short* __restrict__ Hout,
                                              const int* __restrict__ ei,
                                              const float* __restrict__ s_s,
                                              const float* __restrict__ s_d,
                                              int* __restrict__ cursor,
                                              int* __restrict__ esrc,
                                              float* __restrict__ escore) {
  int b = blockIdx.x;
  if (b >= 948) {                        // scatter edges into CSR
    int e = (b - 948) * 256 + threadIdx.x;
    if (e < NEDGE) {
      int src = ei[e], dst = ei[NEDGE + e];
      float v = s_s[src] + s_d[dst];
      v = v > 0.f ? v : SLOPE * v;
      int pos = atomicAdd(cursor + dst, 1);
      esrc[pos] = src;
      escore[pos] = v;
    }
    return;
  }
  // ---- GEMM: tile 128(M) x 64(N), BK=32, 4 waves in 2x2 ----
  __shared__ __align__(16) unsigned short As[128 * 32];   // 8 KB
  __shared__ __align__(16) unsigned short Bs[64 * 32];    // 4 KB
  int tid = threadIdx.x, lane = tid & 63, wid = tid >> 6;
  int m0 = (b % 79) * 128, n0 = (b / 79) * 64;
  int wm = wid >> 1, wn = wid & 1;
  int q = lane >> 4, lr = lane & 15;

  f32x4 acc[4][2];
#pragma unroll
  for (int i = 0; i < 4; ++i)
#pragma unroll
    for (int j = 0; j < 2; ++j) acc[i][j] = 0.f;

  for (int kt = 0; kt < 24; ++kt) {
    int k0 = kt * 32;
    // A-tile: 512 16B chunks, 2 per thread
#pragma unroll
    for (int t = 0; t < 2; ++t) {
      int c = wid * 128 + t * 64 + lane;
      int row = c >> 2, kk = (c & 3) << 3;
      int grow = m0 + row;
      grow = grow <= NNODE - 1 ? grow : NNODE - 1;
      gl2lds16(A + (size_t)grow * HDIM + k0 + kk, As + (size_t)wid * 1024 + t * 512);
    }
    // B-tile: 256 16B chunks, 1 per thread (n0+row < 768 always)
    {
      int c = wid * 64 + lane;
      int row = c >> 2, kk = (c & 3) << 3;
      gl2lds16(BT + (size_t)(n0 + row) * HDIM + k0 + kk, Bs + (size_t)wid * 512);
    }
    __syncthreads();
    bf16x8 a[4], bb[2];
#pragma unroll
    for (int i = 0; i < 4; ++i)
      a[i] = *(const bf16x8*)(As + (wm * 64 + i * 16 + lr) * 32 + q * 8);
#pragma unroll
    for (int j = 0; j < 2; ++j)
      bb[j] = *(const bf16x8*)(Bs + (wn * 32 + j * 16 + lr) * 32 + q * 8);
#pragma unroll
    for (int i = 0; i < 4; ++i)
#pragma unroll
      for (int j = 0; j < 2; ++j)
        acc[i][j] = __builtin_amdgcn_mfma_f32_16x16x32_bf16(a[i], bb[j], acc[i][j], 0, 0, 0);
    __syncthreads();
  }
#pragma unroll
  for (int i = 0; i < 4; ++i) {
    int mbase = m0 + wm * 64 + i * 16 + q * 4;
#pragma unroll
    for (int j = 0; j < 2; ++j) {
      int n = n0 + wn * 32 + j * 16 + lr;
#pragma unroll
      for (int rg = 0; rg < 4; ++rg) {
        int m = mbase + rg;
        if (m < NNODE) Hout[(size_t)m * HDIM + n] = f2bf(acc[i][j][rg]);
      }
    }
  }
}

// ---------- L4: aggregate per dst node + fused finalize (192 thr, ushort4/float4) ----------
__global__ __launch_bounds__(192) void k_aggregate(const int* __restrict__ start,
                                                   const int* __restrict__ esrc,
                                                   const float* __restrict__ escore,
                                                   const unsigned short* __restrict__ h,
                                                   const float* __restrict__ feat,
                                                   float* __restrict__ fo) {
  int n = blockIdx.x, t = threadIdx.x;   // t in 0..191, each owns 4 columns
  int b = start[n], en = start[n + 1];
  float m = -3.4e38f;
  for (int e = b; e < en; ++e) m = fmaxf(m, escore[e]);
  float a0 = 0.f, a1 = 0.f, a2 = 0.f, a3 = 0.f, den = 0.f;
  for (int e = b; e < en; ++e) {
    float ex = __expf(escore[e] - m);
    den += ex;
    ushort4 hv = *(const ushort4*)(h + (size_t)esrc[e] * HDIM + t * 4);
    a0 += ex * bf2f(hv.x);
    a1 += ex * bf2f(hv.y);
    a2 += ex * bf2f(hv.z);
    a3 += ex * bf2f(hv.w);
  }
  float inv = 1.f / (den + 1e-16f);      // deg==0: acc=0 -> fo=feat
  size_t o = (size_t)n * HDIM + t * 4;
  float4 f = *(const float4*)(feat + o);
  f.x += a0 * inv; f.y += a1 * inv; f.z += a2 * inv; f.w += a3 * inv;
  *(float4*)(fo + o) = f;
}

// ---------- L5: gather: out[b,s,:]  (f32, 16B chunks) ----------
__global__ __launch_bounds__(256) void k_gather(const int* __restrict__ x,
                                                const float* __restrict__ orig,
                                                const float* __restrict__ nw,
                                                const float* __restrict__ soft,
                                                const float* __restrict__ fo,
                                                uint4* __restrict__ out) {
  int chunk = blockIdx.x * 256 + threadIdx.x;     // 192 chunks/row, 32768 rows
  int row = chunk / 192;
  int c4 = chunk - row * 192;
  int s = row & 511;
  const float* g;
  if (s < 8) {
    g = soft + (size_t)s * HDIM + c4 * 4;
  } else {
    int idx = x[row];
    if (idx < VOCAB) g = orig + (size_t)idx * HDIM + c4 * 4;
    else if (idx < VOCAB + NNODE) g = fo + (size_t)(idx - VOCAB) * HDIM + c4 * 4;
    else g = nw + (size_t)(NROWS - 1) * HDIM + c4 * 4;
  }
  out[chunk] = *(const uint4*)g;
}

// ---------- launch ----------
extern "C" void kernel_launch(void* const* d_in, const int* in_sizes, int n_in,
                              void* d_out, int out_size, void* d_ws, size_t ws_size,
                              hipStream_t stream) {
  const int* x    = (const int*)d_in[0];
  const int* ei   = (const int*)d_in[1];
  const float* og = (const float*)d_in[2];
  const float* nw = (const float*)d_in[3];
  const float* sp = (const float*)d_in[4];
  const float* W  = (const float*)d_in[5];
  const float* as = (const float*)d_in[6];
  const float* ad = (const float*)d_in[7];
  const float* feat = nw + HDIM;                  // new_weight rows 1..10002

  char* ws = (char*)d_ws;
  unsigned short* hbuf   = (unsigned short*)(ws + OFF_H);
  unsigned short* featbf = (unsigned short*)(ws + OFF_FB);
  float* fo              = (float*)(ws + OFF_FO);
  unsigned short* wT     = (unsigned short*)(ws + OFF_WT);
  float* wa_s            = (float*)(ws + OFF_WAS);
  float* wa_d            = (float*)(ws + OFF_WAD);
  float* s_s             = (float*)(ws + OFF_SS);
  float* s_d             = (float*)(ws + OFF_SD);
  int* count             = (int*)(ws + OFF_CNT);
  int* startArr          = (int*)(ws + OFF_START);
  int* cursor            = (int*)(ws + OFF_CUR);
  int* esrc              = (int*)(ws + OFF_ESRC);
  float* escore          = (float*)(ws + OFF_ESC);

  (void)hipMemsetAsync(count, 0, SZ_N4, stream);
  // L1: prep (768 blocks) + hist (196 blocks)
  k_front<<<964, 256, 0, stream>>>(W, as, ad, ei, wT, wa_s, wa_d, count);
  // L2: convert+scores (2501 blocks) + scan (block 2501)
  k_mid<<<2502, 256, 0, stream>>>(feat, wa_s, wa_d, featbf, s_s, s_d,
                                  count, startArr, cursor);
  // L3: gemm 79x12=948 blocks + scatter 196 blocks
  k_main<<<1144, 256, 0, stream>>>(featbf, wT, hbuf, ei, s_s, s_d,
                                   cursor, esrc, escore);
  // L4: aggregate
  k_aggregate<<<NNODE, 192, 0, stream>>>(startArr, esrc, escore, hbuf, feat, fo);
  // L5: gather
  k_gather<<<(32768 * 192) / 256, 256, 0, stream>>>(x, og, nw, sp, fo, (uint4*)d_out);
}